// Round 5
// baseline (848.221 us; speedup 1.0000x reference)
//
#include <hip/hip_runtime.h>

#define N_NODES 200000
#define N_EDGES 6400000
#define K_BUCKETS 256
#define BUCKET 784          // 256*784 = 200704 >= 200000; dl < 1024
#define NSB 800             // chunks
#define CHUNK 8000          // NSB*CHUNK == N_EDGES exactly

__device__ __forceinline__ unsigned short f2bf(float x) {
    unsigned u = __float_as_uint(x);
    u += 0x7fffu + ((u >> 16) & 1u);      // RNE to bf16
    return (unsigned short)(u >> 16);
}
__device__ __forceinline__ float bf2f(unsigned short h) {
    return __uint_as_float((unsigned)h << 16);
}

// ---------------- fast path ----------------

__global__ __launch_bounds__(256) void copy_x(const float4* __restrict__ z,
                                              float4* __restrict__ x_out)
{
    int n = blockIdx.x * 256 + threadIdx.x;
    if (n < N_NODES) x_out[n] = z[n];
}

// per-chunk bucket histogram, transposed: counts_T[k*NSB + sb]
__global__ __launch_bounds__(256) void hist_kernel(const int* __restrict__ dst,
                                                   int* __restrict__ counts_T)
{
    __shared__ int cnt[K_BUCKETS];
    int tid = threadIdx.x, sb = blockIdx.x;
    cnt[tid] = 0;
    __syncthreads();
    int e0 = sb * CHUNK;
    for (int i = tid; i < CHUNK; i += 256)
        atomicAdd(&cnt[dst[e0 + i] / BUCKET], 1);
    __syncthreads();
    counts_T[(size_t)tid * NSB + sb] = cnt[tid];
}

// per-bucket exclusive scan across chunks
__global__ __launch_bounds__(256) void scan_cols(const int* __restrict__ counts_T,
                                                 int* __restrict__ baseRel_T,
                                                 int* __restrict__ tot)
{
    __shared__ int buf[256];
    __shared__ int carry_s;
    int k = blockIdx.x, tid = threadIdx.x;
    if (tid == 0) carry_s = 0;
    __syncthreads();
    const int* col = counts_T + (size_t)k * NSB;
    int* outc = baseRel_T + (size_t)k * NSB;
    for (int base = 0; base < NSB; base += 256) {
        int idx = base + tid;
        int v = (idx < NSB) ? col[idx] : 0;
        buf[tid] = v;
        __syncthreads();
        for (int off = 1; off < 256; off <<= 1) {
            int t = (tid >= off) ? buf[tid - off] : 0;
            __syncthreads();
            buf[tid] += t;
            __syncthreads();
        }
        int incl = buf[tid];
        if (idx < NSB) outc[idx] = carry_s + incl - v;
        __syncthreads();
        if (tid == 255) carry_s += incl;
        __syncthreads();
    }
    if (tid == 255) tot[k] = carry_s;
}

__global__ __launch_bounds__(256) void scan_tot(const int* __restrict__ tot,
                                                int* __restrict__ bstart)
{
    __shared__ int buf[256];
    int tid = threadIdx.x;
    int v = tot[tid];
    buf[tid] = v;
    __syncthreads();
    for (int off = 1; off < 256; off <<= 1) {
        int t = (tid >= off) ? buf[tid - off] : 0;
        __syncthreads();
        buf[tid] += t;
        __syncthreads();
    }
    bstart[tid] = buf[tid] - v;
    if (tid == 255) bstart[256] = buf[255];
}

// counting-sort scatter: coalesced writes of pack + bf16{r,rhat}
__global__ __launch_bounds__(256) void scatter_kernel(
    const int* __restrict__ src, const int* __restrict__ dst,
    const float* __restrict__ r, const float* __restrict__ r_hat,
    const int* __restrict__ baseRel_T, const int* __restrict__ bstart,
    int* __restrict__ packedA, ushort4* __restrict__ rc)
{
    __shared__ int cnt[K_BUCKETS];
    __shared__ int cur[K_BUCKETS];
    __shared__ int delta[K_BUCKETS];
    __shared__ int scanbuf[256];
    __shared__ unsigned char  kbuf[CHUNK];   // edge -> bucket
    __shared__ unsigned char  skb[CHUNK];    // slot -> bucket
    __shared__ unsigned short lperm[CHUNK];  // slot -> edge local idx

    int tid = threadIdx.x, sb = blockIdx.x;
    cnt[tid] = 0;
    __syncthreads();
    int e0 = sb * CHUNK;

    // pass A: count, remember bucket per edge
    for (int i = tid; i < CHUNK; i += 256) {
        int k = dst[e0 + i] / BUCKET;
        kbuf[i] = (unsigned char)k;
        atomicAdd(&cnt[k], 1);
    }
    __syncthreads();

    // exclusive scan of cnt -> localBase; delta maps slot -> global pos
    int v = cnt[tid];
    scanbuf[tid] = v;
    __syncthreads();
    for (int off = 1; off < 256; off <<= 1) {
        int t = (tid >= off) ? scanbuf[tid - off] : 0;
        __syncthreads();
        scanbuf[tid] += t;
        __syncthreads();
    }
    int localBase = scanbuf[tid] - v;
    int gBase = bstart[tid] + baseRel_T[(size_t)tid * NSB + sb];
    delta[tid] = gBase - localBase;
    cur[tid] = localBase;
    __syncthreads();

    // pass B: assign slots
    for (int i = tid; i < CHUNK; i += 256) {
        int k = kbuf[i];
        int slot = atomicAdd(&cur[k], 1);
        lperm[slot] = (unsigned short)i;
        skb[slot] = (unsigned char)k;
    }
    __syncthreads();

    // pass C: emit records in slot order -> coalesced global stores
    for (int s = tid; s < CHUNK; s += 256) {
        int j = lperm[s];
        int k = skb[s];
        int e = e0 + j;
        int gpos = delta[k] + s;
        int d = dst[e];
        int dl = d - k * BUCKET;
        int sn = src[e];
        float rv = r[e];
        size_t he = 3 * (size_t)e;
        float h0 = r_hat[he], h1 = r_hat[he + 1], h2 = r_hat[he + 2];
        packedA[gpos] = (sn << 10) | dl;
        ushort4 rcv;
        rcv.x = f2bf(rv); rcv.y = f2bf(h0); rcv.z = f2bf(h1); rcv.w = f2bf(h2);
        rc[gpos] = rcv;
    }
}

// static per-node aggregates: Y = sum z0[src], aux = {R=sum r, H=sum rhat}, deg
__global__ __launch_bounds__(1024) void agg0_kernel(
    const int* __restrict__ packedA, const ushort4* __restrict__ rc,
    const int* __restrict__ bstart, const float4* __restrict__ z0,
    float4* __restrict__ Y, float4* __restrict__ aux, float* __restrict__ deg)
{
    __shared__ float Yx[BUCKET], Yy[BUCKET], Yz[BUCKET], Yw[BUCKET];
    __shared__ float Rl[BUCKET], H0[BUCKET], H1[BUCKET], H2[BUCKET];
    __shared__ float Dl[BUCKET];
    int tid = threadIdx.x, k = blockIdx.x;
    int nbase = k * BUCKET;
    int nn = min(BUCKET, N_NODES - nbase);

    for (int i = tid; i < BUCKET; i += 1024) {
        Yx[i] = 0.f; Yy[i] = 0.f; Yz[i] = 0.f; Yw[i] = 0.f;
        Rl[i] = 0.f; H0[i] = 0.f; H1[i] = 0.f; H2[i] = 0.f; Dl[i] = 0.f;
    }
    __syncthreads();

    int estart = bstart[k], eend = bstart[k + 1];
    for (int j = estart + tid; j < eend; j += 1024) {
        int pack = packedA[j];
        int s = pack >> 10;
        int dl = pack & 1023;
        float4 zs = z0[s];
        ushort4 rcv = rc[j];
        atomicAdd(&Yx[dl], zs.x);
        atomicAdd(&Yy[dl], zs.y);
        atomicAdd(&Yz[dl], zs.z);
        atomicAdd(&Yw[dl], zs.w);
        atomicAdd(&Rl[dl], bf2f(rcv.x));
        atomicAdd(&H0[dl], bf2f(rcv.y));
        atomicAdd(&H1[dl], bf2f(rcv.z));
        atomicAdd(&H2[dl], bf2f(rcv.w));
        atomicAdd(&Dl[dl], 1.0f);
    }
    __syncthreads();

    for (int i = tid; i < nn; i += 1024) {
        float4 yv; yv.x = Yx[i]; yv.y = Yy[i]; yv.z = Yz[i]; yv.w = Yw[i];
        Y[nbase + i] = yv;
        float4 av; av.x = Rl[i]; av.y = H0[i]; av.z = H1[i]; av.w = H2[i];
        aux[nbase + i] = av;
        deg[nbase + i] = Dl[i];
    }
}

// per-layer scalar SpMV: t[n] = sum_{e:dst=n} S[src_e]
__global__ __launch_bounds__(1024) void spmv_kernel(
    const int* __restrict__ packedA, const int* __restrict__ bstart,
    const float* __restrict__ S, float* __restrict__ t)
{
    __shared__ float tsl[BUCKET];
    int tid = threadIdx.x, k = blockIdx.x;
    int nbase = k * BUCKET;
    int nn = min(BUCKET, N_NODES - nbase);
    for (int i = tid; i < BUCKET; i += 1024) tsl[i] = 0.f;
    __syncthreads();
    int estart = bstart[k], eend = bstart[k + 1];
    for (int j = estart + tid; j < eend; j += 1024) {
        int pack = packedA[j];
        int s = pack >> 10;
        int dl = pack & 1023;
        atomicAdd(&tsl[dl], S[s]);
    }
    __syncthreads();
    for (int i = tid; i < nn; i += 1024) t[nbase + i] = tsl[i];
}

// node-wise layer update:
// agg = a.Y + A*t + deg*(q.z0 + B*S) + w8*R + w9..11.H + b*deg ; S' = S + agg
__global__ __launch_bounds__(256) void node_kernel(
    const float4* __restrict__ z0, const float4* __restrict__ Y,
    const float4* __restrict__ aux, const float* __restrict__ deg,
    const float* __restrict__ t, const float* __restrict__ Sin,
    float* __restrict__ Sout,
    const float* __restrict__ W, const float* __restrict__ b,
    int layer, int first, int last, float4* __restrict__ z_out)
{
    int n = blockIdx.x * 256 + threadIdx.x;
    if (n >= N_NODES) return;
    const float* Wl = W + 12 * layer;
    float a0 = Wl[0], a1 = Wl[1], a2 = Wl[2], a3 = Wl[3];
    float q0 = Wl[4], q1 = Wl[5], q2 = Wl[6], q3 = Wl[7];
    float w8 = Wl[8], w9 = Wl[9], w10 = Wl[10], w11 = Wl[11];
    float bias = b[layer];
    float A = a0 + a1 + a2 + a3, B = q0 + q1 + q2 + q3;
    float4 zv = z0[n], Yv = Y[n], av = aux[n];
    float dg = deg[n];
    float S  = first ? 0.0f : Sin[n];
    float tv = first ? 0.0f : t[n];
    float agg = a0 * Yv.x + a1 * Yv.y + a2 * Yv.z + a3 * Yv.w
              + A * tv
              + dg * (q0 * zv.x + q1 * zv.y + q2 * zv.z + q3 * zv.w + B * S)
              + w8 * av.x + w9 * av.y + w10 * av.z + w11 * av.w + bias * dg;
    float Sn = S + agg;
    Sout[n] = Sn;
    if (last) {
        float4 o = zv;
        o.x += Sn; o.y += Sn; o.z += Sn; o.w += Sn;
        z_out[n] = o;
    }
}

// ---------------- fallback (round-2) ----------------

__global__ __launch_bounds__(256) void init_kernel(
    const float4* __restrict__ z_in, float4* __restrict__ z_cur,
    float4* __restrict__ x_out, float* __restrict__ agg)
{
    int n = blockIdx.x * blockDim.x + threadIdx.x;
    if (n < N_NODES) {
        float4 vv = z_in[n];
        z_cur[n] = vv; x_out[n] = vv; agg[n] = 0.0f;
    }
}

__global__ __launch_bounds__(256) void edge_kernel(
    const float* __restrict__ z, const float* __restrict__ r,
    const float* __restrict__ r_hat, const int* __restrict__ src,
    const int* __restrict__ dst, const float* __restrict__ Wl,
    const float* __restrict__ bl, float* __restrict__ agg)
{
    int e = blockIdx.x * blockDim.x + threadIdx.x;
    if (e >= N_EDGES) return;
    float w0 = Wl[0], w1 = Wl[1], w2 = Wl[2], w3 = Wl[3];
    float w4 = Wl[4], w5 = Wl[5], w6 = Wl[6], w7 = Wl[7];
    float w8 = Wl[8], w9 = Wl[9], w10 = Wl[10], w11 = Wl[11];
    float bias = bl[0];
    int s = src[e], d = dst[e];
    float4 zs = ((const float4*)z)[s];
    float4 zd = ((const float4*)z)[d];
    float rv = r[e];
    const float* rh = r_hat + 3 * (size_t)e;
    float msg = w0*zs.x + w1*zs.y + w2*zs.z + w3*zs.w
              + w4*zd.x + w5*zd.y + w6*zd.z + w7*zd.w
              + w8*rv + w9*rh[0] + w10*rh[1] + w11*rh[2] + bias;
    unsafeAtomicAdd(&agg[d], msg);
}

__global__ __launch_bounds__(256) void node_update(float4* __restrict__ z_cur,
                                                   float* __restrict__ agg)
{
    int n = blockIdx.x * blockDim.x + threadIdx.x;
    if (n < N_NODES) {
        float a = agg[n]; float4 vv = z_cur[n];
        vv.x += a; vv.y += a; vv.z += a; vv.w += a;
        z_cur[n] = vv; agg[n] = 0.0f;
    }
}

__global__ __launch_bounds__(256) void final_update(const float4* __restrict__ z_cur,
                                                    const float* __restrict__ agg,
                                                    float4* __restrict__ z_out)
{
    int n = blockIdx.x * blockDim.x + threadIdx.x;
    if (n < N_NODES) {
        float a = agg[n]; float4 vv = z_cur[n];
        vv.x += a; vv.y += a; vv.z += a; vv.w += a;
        z_out[n] = vv;
    }
}

// ---------------- launch ----------------

extern "C" void kernel_launch(void* const* d_in, const int* in_sizes, int n_in,
                              void* d_out, int out_size, void* d_ws, size_t ws_size,
                              hipStream_t stream)
{
    const float* z     = (const float*)d_in[0];
    const float* r     = (const float*)d_in[1];
    const float* r_hat = (const float*)d_in[2];
    const float* W     = (const float*)d_in[3];
    const float* b     = (const float*)d_in[4];
    const int*   src   = (const int*)d_in[5];
    const int*   dst   = (const int*)d_in[6];
    float* out = (float*)d_out;

    char* ws = (char*)d_ws;
    size_t off = 0;
    auto alloc = [&](size_t bytes) {
        void* p = ws + off;
        off += (bytes + 15) & ~(size_t)15;
        return p;
    };
    int*     packedA   = (int*)alloc((size_t)N_EDGES * 4);
    ushort4* rc        = (ushort4*)alloc((size_t)N_EDGES * 8);
    int*     counts_T  = (int*)alloc((size_t)K_BUCKETS * NSB * 4);
    int*     baseRel_T = (int*)alloc((size_t)K_BUCKETS * NSB * 4);
    int*     tot       = (int*)alloc((size_t)K_BUCKETS * 4);
    int*     bstart    = (int*)alloc((size_t)(K_BUCKETS + 1) * 4);
    float4*  Y         = (float4*)alloc((size_t)N_NODES * 16);
    float4*  aux       = (float4*)alloc((size_t)N_NODES * 16);
    float*   deg       = (float*)alloc((size_t)N_NODES * 4);
    float*   Sa        = (float*)alloc((size_t)N_NODES * 4);
    float*   Sb        = (float*)alloc((size_t)N_NODES * 4);
    float*   tbuf      = (float*)alloc((size_t)N_NODES * 4);
    size_t required = off;

    dim3 nblk((N_NODES + 255) / 256);

    if (ws_size >= required) {
        copy_x<<<nblk, 256, 0, stream>>>((const float4*)z,
                                         (float4*)(out + 4 * (size_t)N_NODES));
        hist_kernel<<<NSB, 256, 0, stream>>>(dst, counts_T);
        scan_cols<<<K_BUCKETS, 256, 0, stream>>>(counts_T, baseRel_T, tot);
        scan_tot<<<1, 256, 0, stream>>>(tot, bstart);
        scatter_kernel<<<NSB, 256, 0, stream>>>(src, dst, r, r_hat,
                                                baseRel_T, bstart, packedA, rc);
        agg0_kernel<<<K_BUCKETS, 1024, 0, stream>>>(packedA, rc, bstart,
                                                    (const float4*)z, Y, aux, deg);
        // layer 0: S0 = 0, t0 = 0 -> node-wise only
        node_kernel<<<nblk, 256, 0, stream>>>(
            (const float4*)z, Y, aux, deg, tbuf, Sa, Sa, W, b, 0, 1, 0, (float4*)out);
        // layer 1
        spmv_kernel<<<K_BUCKETS, 1024, 0, stream>>>(packedA, bstart, Sa, tbuf);
        node_kernel<<<nblk, 256, 0, stream>>>(
            (const float4*)z, Y, aux, deg, tbuf, Sa, Sb, W, b, 1, 0, 0, (float4*)out);
        // layer 2
        spmv_kernel<<<K_BUCKETS, 1024, 0, stream>>>(packedA, bstart, Sb, tbuf);
        node_kernel<<<nblk, 256, 0, stream>>>(
            (const float4*)z, Y, aux, deg, tbuf, Sb, Sa, W, b, 2, 0, 1, (float4*)out);
    } else {
        // fallback: round-2 path
        float* agg   = (float*)d_ws;
        float* z_cur = agg + N_NODES;
        dim3 eblk((N_EDGES + 255) / 256);
        init_kernel<<<nblk, 256, 0, stream>>>(
            (const float4*)z, (float4*)z_cur,
            (float4*)(out + 4 * (size_t)N_NODES), agg);
        for (int i = 0; i < 3; ++i) {
            edge_kernel<<<eblk, 256, 0, stream>>>(
                z_cur, r, r_hat, src, dst, W + 12 * i, b + i, agg);
            if (i < 2)
                node_update<<<nblk, 256, 0, stream>>>((float4*)z_cur, agg);
            else
                final_update<<<nblk, 256, 0, stream>>>(
                    (const float4*)z_cur, agg, (float4*)out);
        }
    }
}

// Round 6
// 407.496 us; speedup vs baseline: 2.0815x; 2.0815x over previous
//
#include <hip/hip_runtime.h>

#define N_NODES 200000
#define N_EDGES 6400000
#define K_BUCKETS 256
#define BUCKET 784          // 256*784 = 200704 >= 200000; dl < 1024
#define NSB 1600            // chunks
#define CHUNK 4000          // NSB*CHUNK == N_EDGES exactly

__device__ __forceinline__ unsigned short f2bf(float x) {
    unsigned u = __float_as_uint(x);
    u += 0x7fffu + ((u >> 16) & 1u);      // RNE to bf16
    return (unsigned short)(u >> 16);
}
__device__ __forceinline__ float bf2f(unsigned short h) {
    return __uint_as_float((unsigned)h << 16);
}

// ---------------- fast path ----------------

// x_out = z0 ; Scum = 0
__global__ __launch_bounds__(256) void copy_x_prep(const float4* __restrict__ z,
                                                   float4* __restrict__ x_out,
                                                   float* __restrict__ Scum)
{
    int n = blockIdx.x * 256 + threadIdx.x;
    if (n < N_NODES) { x_out[n] = z[n]; Scum[n] = 0.0f; }
}

// per-chunk bucket histogram, transposed: counts_T[k*NSB + sb]
__global__ __launch_bounds__(256) void hist_kernel(const int* __restrict__ dst,
                                                   int* __restrict__ counts_T)
{
    __shared__ int cnt[K_BUCKETS];
    int tid = threadIdx.x, sb = blockIdx.x;
    cnt[tid] = 0;
    __syncthreads();
    int e0 = sb * CHUNK;
    for (int i = tid; i < CHUNK; i += 256)
        atomicAdd(&cnt[dst[e0 + i] / BUCKET], 1);
    __syncthreads();
    counts_T[(size_t)tid * NSB + sb] = cnt[tid];
}

// per-bucket exclusive scan across chunks
__global__ __launch_bounds__(256) void scan_cols(const int* __restrict__ counts_T,
                                                 int* __restrict__ baseRel_T,
                                                 int* __restrict__ tot)
{
    __shared__ int buf[256];
    __shared__ int carry_s;
    int k = blockIdx.x, tid = threadIdx.x;
    if (tid == 0) carry_s = 0;
    __syncthreads();
    const int* col = counts_T + (size_t)k * NSB;
    int* outc = baseRel_T + (size_t)k * NSB;
    for (int base = 0; base < NSB; base += 256) {
        int idx = base + tid;
        int v = (idx < NSB) ? col[idx] : 0;
        buf[tid] = v;
        __syncthreads();
        for (int off = 1; off < 256; off <<= 1) {
            int t = (tid >= off) ? buf[tid - off] : 0;
            __syncthreads();
            buf[tid] += t;
            __syncthreads();
        }
        int incl = buf[tid];
        if (idx < NSB) outc[idx] = carry_s + incl - v;
        __syncthreads();
        if (tid == 255) carry_s += incl;
        __syncthreads();
    }
    if (tid == 255) tot[k] = carry_s;
}

__global__ __launch_bounds__(256) void scan_tot(const int* __restrict__ tot,
                                                int* __restrict__ bstart)
{
    __shared__ int buf[256];
    int tid = threadIdx.x;
    int v = tot[tid];
    buf[tid] = v;
    __syncthreads();
    for (int off = 1; off < 256; off <<= 1) {
        int t = (tid >= off) ? buf[tid - off] : 0;
        __syncthreads();
        buf[tid] += t;
        __syncthreads();
    }
    bstart[tid] = buf[tid] - v;
    if (tid == 255) bstart[256] = buf[255];
}

// counting-sort scatter: ALL global reads coalesced; permutation done in LDS;
// 4 coalesced output streams (packedA, c0, c1, c2).
__global__ __launch_bounds__(256) void scatter_kernel(
    const int* __restrict__ src, const int* __restrict__ dst,
    const float* __restrict__ r, const float* __restrict__ r_hat,
    const float* __restrict__ W, const float* __restrict__ b,
    const int* __restrict__ baseRel_T, const int* __restrict__ bstart,
    int* __restrict__ packedA,
    unsigned short* __restrict__ c0a, unsigned short* __restrict__ c1a,
    unsigned short* __restrict__ c2a)
{
    __shared__ int cnt[K_BUCKETS];
    __shared__ int cur[K_BUCKETS];
    __shared__ int delta[K_BUCKETS];
    __shared__ int scanbuf[256];
    __shared__ int            lpack[CHUNK];   // slot -> packed (src<<10|dl)
    __shared__ unsigned short lc0[CHUNK];
    __shared__ unsigned short lc1[CHUNK];
    __shared__ unsigned short lc2[CHUNK];
    __shared__ unsigned char  skb[CHUNK];     // slot -> bucket

    int tid = threadIdx.x, sb = blockIdx.x;
    cnt[tid] = 0;
    __syncthreads();
    int e0 = sb * CHUNK;

    // pass A: count buckets (coalesced dst read)
    for (int i = tid; i < CHUNK; i += 256)
        atomicAdd(&cnt[dst[e0 + i] / BUCKET], 1);
    __syncthreads();

    // exclusive scan of cnt -> localBase; delta maps local slot -> global pos
    int v = cnt[tid];
    scanbuf[tid] = v;
    __syncthreads();
    for (int off = 1; off < 256; off <<= 1) {
        int t = (tid >= off) ? scanbuf[tid - off] : 0;
        __syncthreads();
        scanbuf[tid] += t;
        __syncthreads();
    }
    int localBase = scanbuf[tid] - v;
    int gBase = bstart[tid] + baseRel_T[(size_t)tid * NSB + sb];
    delta[tid] = gBase - localBase;
    cur[tid] = localBase;
    __syncthreads();

    float w8_0 = W[8],  w9_0 = W[9],  w10_0 = W[10], w11_0 = W[11], b0 = b[0];
    float w8_1 = W[20], w9_1 = W[21], w10_1 = W[22], w11_1 = W[23], b1 = b[1];
    float w8_2 = W[32], w9_2 = W[33], w10_2 = W[34], w11_2 = W[35], b2 = b[2];

    // pass B: coalesced reads, scattered LDS writes to sorted slot
    for (int i = tid; i < CHUNK; i += 256) {
        int e = e0 + i;
        int d = dst[e];                        // L1-hot (read in pass A)
        int k = d / BUCKET;
        int dl = d - k * BUCKET;
        int slot = atomicAdd(&cur[k], 1);
        int sn = src[e];
        float rv = r[e];
        size_t he = 3 * (size_t)e;
        float h0 = r_hat[he], h1 = r_hat[he + 1], h2 = r_hat[he + 2];
        lpack[slot] = (sn << 10) | dl;
        lc0[slot] = f2bf(w8_0 * rv + w9_0 * h0 + w10_0 * h1 + w11_0 * h2 + b0);
        lc1[slot] = f2bf(w8_1 * rv + w9_1 * h0 + w10_1 * h1 + w11_1 * h2 + b1);
        lc2[slot] = f2bf(w8_2 * rv + w9_2 * h0 + w10_2 * h1 + w11_2 * h2 + b2);
        skb[slot] = (unsigned char)k;
    }
    __syncthreads();

    // pass C: sequential LDS reads, coalesced global stores
    for (int s = tid; s < CHUNK; s += 256) {
        int k = skb[s];
        int gpos = delta[k] + s;
        packedA[gpos] = lpack[s];
        c0a[gpos] = lc0[s];
        c1a[gpos] = lc1[s];
        c2a[gpos] = lc2[s];
    }
}

// per-node scalars for layer i: u = a.z0 + sum(a)*S ; v = q.z0 + sum(q)*S
__global__ __launch_bounds__(256) void uv_kernel(
    const float4* __restrict__ z0, const float* __restrict__ Scum,
    const float* __restrict__ Wl,
    float* __restrict__ u, float* __restrict__ v)
{
    int n = blockIdx.x * 256 + threadIdx.x;
    if (n >= N_NODES) return;
    float a0 = Wl[0], a1 = Wl[1], a2 = Wl[2], a3 = Wl[3];
    float q0 = Wl[4], q1 = Wl[5], q2 = Wl[6], q3 = Wl[7];
    float A = a0 + a1 + a2 + a3, B = q0 + q1 + q2 + q3;
    float4 zv = z0[n];
    float S = Scum[n];
    u[n] = a0 * zv.x + a1 * zv.y + a2 * zv.z + a3 * zv.w + A * S;
    v[n] = q0 * zv.x + q1 * zv.y + q2 * zv.z + q3 * zv.w + B * S;
}

// scalar SpMV layer: one block owns one bucket; 1 LDS atomic per edge
__global__ __launch_bounds__(1024) void layer_kernel(
    const int* __restrict__ packedA, const unsigned short* __restrict__ cpl,
    const int* __restrict__ bstart,
    const float* __restrict__ u, const float* __restrict__ v,
    float* __restrict__ Scum, int final_layer,
    const float4* __restrict__ z0, float4* __restrict__ z_out)
{
    __shared__ float vsl[BUCKET];
    __shared__ float aggsl[BUCKET];
    int tid = threadIdx.x, k = blockIdx.x;
    int nbase = k * BUCKET;
    int nn = min(BUCKET, N_NODES - nbase);

    for (int i = tid; i < nn; i += 1024) { vsl[i] = v[nbase + i]; aggsl[i] = 0.0f; }
    __syncthreads();

    int estart = bstart[k], eend = bstart[k + 1];
    for (int j = estart + tid; j < eend; j += 1024) {
        int pack = packedA[j];
        int s = pack >> 10;
        int dl = pack & 1023;
        float t = u[s] + vsl[dl] + bf2f(cpl[j]);
        atomicAdd(&aggsl[dl], t);                        // ds_add_f32
    }
    __syncthreads();

    for (int i = tid; i < nn; i += 1024) {
        float S = Scum[nbase + i] + aggsl[i];
        Scum[nbase + i] = S;
        if (final_layer) {
            float4 zv = z0[nbase + i];
            zv.x += S; zv.y += S; zv.z += S; zv.w += S;
            z_out[nbase + i] = zv;
        }
    }
}

// ---------------- fallback (round-2) ----------------

__global__ __launch_bounds__(256) void init_kernel(
    const float4* __restrict__ z_in, float4* __restrict__ z_cur,
    float4* __restrict__ x_out, float* __restrict__ agg)
{
    int n = blockIdx.x * blockDim.x + threadIdx.x;
    if (n < N_NODES) {
        float4 vv = z_in[n];
        z_cur[n] = vv; x_out[n] = vv; agg[n] = 0.0f;
    }
}

__global__ __launch_bounds__(256) void edge_kernel(
    const float* __restrict__ z, const float* __restrict__ r,
    const float* __restrict__ r_hat, const int* __restrict__ src,
    const int* __restrict__ dst, const float* __restrict__ Wl,
    const float* __restrict__ bl, float* __restrict__ agg)
{
    int e = blockIdx.x * blockDim.x + threadIdx.x;
    if (e >= N_EDGES) return;
    float w0 = Wl[0], w1 = Wl[1], w2 = Wl[2], w3 = Wl[3];
    float w4 = Wl[4], w5 = Wl[5], w6 = Wl[6], w7 = Wl[7];
    float w8 = Wl[8], w9 = Wl[9], w10 = Wl[10], w11 = Wl[11];
    float bias = bl[0];
    int s = src[e], d = dst[e];
    float4 zs = ((const float4*)z)[s];
    float4 zd = ((const float4*)z)[d];
    float rv = r[e];
    const float* rh = r_hat + 3 * (size_t)e;
    float msg = w0*zs.x + w1*zs.y + w2*zs.z + w3*zs.w
              + w4*zd.x + w5*zd.y + w6*zd.z + w7*zd.w
              + w8*rv + w9*rh[0] + w10*rh[1] + w11*rh[2] + bias;
    unsafeAtomicAdd(&agg[d], msg);
}

__global__ __launch_bounds__(256) void node_update(float4* __restrict__ z_cur,
                                                   float* __restrict__ agg)
{
    int n = blockIdx.x * blockDim.x + threadIdx.x;
    if (n < N_NODES) {
        float a = agg[n]; float4 vv = z_cur[n];
        vv.x += a; vv.y += a; vv.z += a; vv.w += a;
        z_cur[n] = vv; agg[n] = 0.0f;
    }
}

__global__ __launch_bounds__(256) void final_update(const float4* __restrict__ z_cur,
                                                    const float* __restrict__ agg,
                                                    float4* __restrict__ z_out)
{
    int n = blockIdx.x * blockDim.x + threadIdx.x;
    if (n < N_NODES) {
        float a = agg[n]; float4 vv = z_cur[n];
        vv.x += a; vv.y += a; vv.z += a; vv.w += a;
        z_out[n] = vv;
    }
}

// ---------------- launch ----------------

extern "C" void kernel_launch(void* const* d_in, const int* in_sizes, int n_in,
                              void* d_out, int out_size, void* d_ws, size_t ws_size,
                              hipStream_t stream)
{
    const float* z     = (const float*)d_in[0];
    const float* r     = (const float*)d_in[1];
    const float* r_hat = (const float*)d_in[2];
    const float* W     = (const float*)d_in[3];
    const float* b     = (const float*)d_in[4];
    const int*   src   = (const int*)d_in[5];
    const int*   dst   = (const int*)d_in[6];
    float* out = (float*)d_out;

    char* ws = (char*)d_ws;
    size_t off = 0;
    auto alloc = [&](size_t bytes) {
        void* p = ws + off;
        off += (bytes + 15) & ~(size_t)15;
        return p;
    };
    int*            packedA   = (int*)alloc((size_t)N_EDGES * 4);
    unsigned short* c0a       = (unsigned short*)alloc((size_t)N_EDGES * 2);
    unsigned short* c1a       = (unsigned short*)alloc((size_t)N_EDGES * 2);
    unsigned short* c2a       = (unsigned short*)alloc((size_t)N_EDGES * 2);
    int*            counts_T  = (int*)alloc((size_t)K_BUCKETS * NSB * 4);
    int*            baseRel_T = (int*)alloc((size_t)K_BUCKETS * NSB * 4);
    int*            tot       = (int*)alloc((size_t)K_BUCKETS * 4);
    int*            bstart    = (int*)alloc((size_t)(K_BUCKETS + 1) * 4);
    float*          Scum      = (float*)alloc((size_t)N_NODES * 4);
    float*          ubuf      = (float*)alloc((size_t)N_NODES * 4);
    float*          vbuf      = (float*)alloc((size_t)N_NODES * 4);
    size_t required = off;

    dim3 nblk((N_NODES + 255) / 256);

    if (ws_size >= required) {
        copy_x_prep<<<nblk, 256, 0, stream>>>(
            (const float4*)z, (float4*)(out + 4 * (size_t)N_NODES), Scum);
        hist_kernel<<<NSB, 256, 0, stream>>>(dst, counts_T);
        scan_cols<<<K_BUCKETS, 256, 0, stream>>>(counts_T, baseRel_T, tot);
        scan_tot<<<1, 256, 0, stream>>>(tot, bstart);
        scatter_kernel<<<NSB, 256, 0, stream>>>(src, dst, r, r_hat, W, b,
                                                baseRel_T, bstart,
                                                packedA, c0a, c1a, c2a);
        const unsigned short* cpl[3] = { c0a, c1a, c2a };
        for (int i = 0; i < 3; ++i) {
            uv_kernel<<<nblk, 256, 0, stream>>>(
                (const float4*)z, Scum, W + 12 * i, ubuf, vbuf);
            layer_kernel<<<K_BUCKETS, 1024, 0, stream>>>(
                packedA, cpl[i], bstart, ubuf, vbuf, Scum,
                (i == 2) ? 1 : 0, (const float4*)z, (float4*)out);
        }
    } else {
        // fallback: round-2 path
        float* agg   = (float*)d_ws;
        float* z_cur = agg + N_NODES;
        dim3 eblk((N_EDGES + 255) / 256);
        init_kernel<<<nblk, 256, 0, stream>>>(
            (const float4*)z, (float4*)z_cur,
            (float4*)(out + 4 * (size_t)N_NODES), agg);
        for (int i = 0; i < 3; ++i) {
            edge_kernel<<<eblk, 256, 0, stream>>>(
                z_cur, r, r_hat, src, dst, W + 12 * i, b + i, agg);
            if (i < 2)
                node_update<<<nblk, 256, 0, stream>>>((float4*)z_cur, agg);
            else
                final_update<<<nblk, 256, 0, stream>>>(
                    (const float4*)z_cur, agg, (float4*)out);
        }
    }
}

// Round 7
// 403.527 us; speedup vs baseline: 2.1020x; 1.0098x over previous
//
#include <hip/hip_runtime.h>

#define N_NODES 200000
#define N_EDGES 6400000
#define K_BUCKETS 256
#define BUCKET 784          // 256*784 = 200704 >= 200000; dl < 1024
#define NSB 3200            // chunks
#define CHUNK 2000          // NSB*CHUNK == N_EDGES exactly
#define P_SPLIT 8           // blocks per bucket in aggregation

__device__ __forceinline__ unsigned short f2bf(float x) {
    unsigned u = __float_as_uint(x);
    u += 0x7fffu + ((u >> 16) & 1u);      // RNE to bf16
    return (unsigned short)(u >> 16);
}
__device__ __forceinline__ float bf2f(unsigned short h) {
    return __uint_as_float((unsigned)h << 16);
}

// ---------------- fast path ----------------

// x_out = z0 ; u0 = a0.z0 ; v0 = q0.z0   (S0 = 0)
__global__ __launch_bounds__(256) void prep_kernel(
    const float4* __restrict__ z, float4* __restrict__ x_out,
    const float* __restrict__ W,
    float* __restrict__ u, float* __restrict__ v)
{
    int n = blockIdx.x * 256 + threadIdx.x;
    if (n >= N_NODES) return;
    float4 zv = z[n];
    x_out[n] = zv;
    float a0 = W[0], a1 = W[1], a2 = W[2], a3 = W[3];
    float q0 = W[4], q1 = W[5], q2 = W[6], q3 = W[7];
    u[n] = a0 * zv.x + a1 * zv.y + a2 * zv.z + a3 * zv.w;
    v[n] = q0 * zv.x + q1 * zv.y + q2 * zv.z + q3 * zv.w;
}

// per-chunk bucket histogram, layout counts[sb*K + k]  (coalesced store)
__global__ __launch_bounds__(256) void hist_kernel(const int* __restrict__ dst,
                                                   int* __restrict__ counts)
{
    __shared__ int cnt[K_BUCKETS];
    int tid = threadIdx.x, sb = blockIdx.x;
    cnt[tid] = 0;
    __syncthreads();
    int e0 = sb * CHUNK;
    for (int i = tid; i < CHUNK; i += 256)
        atomicAdd(&cnt[dst[e0 + i] / BUCKET], 1);
    __syncthreads();
    counts[sb * K_BUCKETS + tid] = cnt[tid];
}

// per-bucket exclusive scan across chunks (strided access, small data)
__global__ __launch_bounds__(256) void scan_cols(const int* __restrict__ counts,
                                                 int* __restrict__ baseRel,
                                                 int* __restrict__ tot)
{
    __shared__ int buf[256];
    __shared__ int carry_s;
    int k = blockIdx.x, tid = threadIdx.x;
    if (tid == 0) carry_s = 0;
    __syncthreads();
    for (int base = 0; base < NSB; base += 256) {
        int idx = base + tid;
        int v = (idx < NSB) ? counts[idx * K_BUCKETS + k] : 0;
        buf[tid] = v;
        __syncthreads();
        for (int off = 1; off < 256; off <<= 1) {
            int t = (tid >= off) ? buf[tid - off] : 0;
            __syncthreads();
            buf[tid] += t;
            __syncthreads();
        }
        int incl = buf[tid];
        if (idx < NSB) baseRel[idx * K_BUCKETS + k] = carry_s + incl - v;
        __syncthreads();
        if (tid == 255) carry_s += incl;
        __syncthreads();
    }
    if (tid == 255) tot[k] = carry_s;
}

__global__ __launch_bounds__(256) void scan_tot(const int* __restrict__ tot,
                                                int* __restrict__ bstart)
{
    __shared__ int buf[256];
    int tid = threadIdx.x;
    int v = tot[tid];
    buf[tid] = v;
    __syncthreads();
    for (int off = 1; off < 256; off <<= 1) {
        int t = (tid >= off) ? buf[tid - off] : 0;
        __syncthreads();
        buf[tid] += t;
        __syncthreads();
    }
    bstart[tid] = buf[tid] - v;
    if (tid == 255) bstart[256] = buf[255];
}

// counting-sort scatter: counts pre-loaded (no count pass); permutation in LDS;
// coalesced outputs packedA (int), c01a (uint: c0|c1<<16), c2a (ushort).
__global__ __launch_bounds__(256) void scatter_kernel(
    const int* __restrict__ src, const int* __restrict__ dst,
    const float* __restrict__ r, const float* __restrict__ r_hat,
    const float* __restrict__ W, const float* __restrict__ b,
    const int* __restrict__ counts, const int* __restrict__ baseRel,
    const int* __restrict__ bstart,
    int* __restrict__ packedA, unsigned* __restrict__ c01a,
    unsigned short* __restrict__ c2a)
{
    __shared__ int cur[K_BUCKETS];
    __shared__ int delta[K_BUCKETS];
    __shared__ int scanbuf[256];
    __shared__ int            lpack[CHUNK];
    __shared__ unsigned       lc01[CHUNK];
    __shared__ unsigned short lc2[CHUNK];
    __shared__ unsigned char  skb[CHUNK];

    int tid = threadIdx.x, sb = blockIdx.x;

    // load per-chunk counts (computed by hist) — replaces a whole count pass
    int v = counts[sb * K_BUCKETS + tid];
    scanbuf[tid] = v;
    __syncthreads();
    for (int off = 1; off < 256; off <<= 1) {
        int t = (tid >= off) ? scanbuf[tid - off] : 0;
        __syncthreads();
        scanbuf[tid] += t;
        __syncthreads();
    }
    int localBase = scanbuf[tid] - v;
    int gBase = bstart[tid] + baseRel[sb * K_BUCKETS + tid];
    delta[tid] = gBase - localBase;
    cur[tid] = localBase;
    __syncthreads();

    float w8_0 = W[8],  w9_0 = W[9],  w10_0 = W[10], w11_0 = W[11], b0 = b[0];
    float w8_1 = W[20], w9_1 = W[21], w10_1 = W[22], w11_1 = W[23], b1 = b[1];
    float w8_2 = W[32], w9_2 = W[33], w10_2 = W[34], w11_2 = W[35], b2 = b[2];

    int e0 = sb * CHUNK;
    // pass B: coalesced global reads, scattered LDS writes to sorted slot
    for (int i = tid; i < CHUNK; i += 256) {
        int e = e0 + i;
        int d = dst[e];
        int k = d / BUCKET;
        int dl = d - k * BUCKET;
        int slot = atomicAdd(&cur[k], 1);
        int sn = src[e];
        float rv = r[e];
        size_t he = 3 * (size_t)e;
        float h0 = r_hat[he], h1 = r_hat[he + 1], h2 = r_hat[he + 2];
        lpack[slot] = (sn << 10) | dl;
        unsigned cc0 = f2bf(w8_0 * rv + w9_0 * h0 + w10_0 * h1 + w11_0 * h2 + b0);
        unsigned cc1 = f2bf(w8_1 * rv + w9_1 * h0 + w10_1 * h1 + w11_1 * h2 + b1);
        lc01[slot] = cc0 | (cc1 << 16);
        lc2[slot]  = f2bf(w8_2 * rv + w9_2 * h0 + w10_2 * h1 + w11_2 * h2 + b2);
        skb[slot]  = (unsigned char)k;
    }
    __syncthreads();

    // pass C: sequential LDS reads, coalesced global stores
    for (int s = tid; s < CHUNK; s += 256) {
        int k = skb[s];
        int gpos = delta[k] + s;
        packedA[gpos] = lpack[s];
        c01a[gpos] = lc01[s];
        c2a[gpos]  = lc2[s];
    }
}

// partial aggregation: P_SPLIT blocks per bucket, LDS partial, dense store
__global__ __launch_bounds__(256) void pagg_kernel(
    const int* __restrict__ packedA, const unsigned* __restrict__ c01a,
    const unsigned short* __restrict__ c2a, const int* __restrict__ bstart,
    const float* __restrict__ u, const float* __restrict__ v,
    int layer, float* __restrict__ partial)
{
    __shared__ float vsl[BUCKET];
    __shared__ float aggsl[BUCKET];
    int tid = threadIdx.x, blk = blockIdx.x;
    int k = blk / P_SPLIT;
    int p = blk - k * P_SPLIT;
    int nbase = k * BUCKET;
    int nn = min(BUCKET, N_NODES - nbase);

    for (int i = tid; i < BUCKET; i += 256) {
        aggsl[i] = 0.0f;
        vsl[i] = (i < nn) ? v[nbase + i] : 0.0f;
    }
    __syncthreads();

    int estart = bstart[k], eend = bstart[k + 1];
    int len = eend - estart;
    int per = (len + P_SPLIT - 1) / P_SPLIT;
    int lo = estart + p * per;
    int hi = min(lo + per, eend);

    for (int j = lo + tid; j < hi; j += 256) {
        int pack = packedA[j];
        int s = pack >> 10;
        int dl = pack & 1023;
        float c = (layer == 2) ? bf2f(c2a[j])
                               : bf2f((unsigned short)(c01a[j] >> (16 * layer)));
        atomicAdd(&aggsl[dl], u[s] + vsl[dl] + c);       // ds_add_f32
    }
    __syncthreads();

    float* pout = partial + (size_t)blk * BUCKET;
    for (int i = tid; i < BUCKET; i += 256) pout[i] = aggsl[i];
}

// finalize layer: S' = S + sum(partials); compute next u,v (or final z)
__global__ __launch_bounds__(256) void fin_kernel(
    const float4* __restrict__ z0, const float* __restrict__ partial,
    const float* __restrict__ Sin, float* __restrict__ Sout,
    const float* __restrict__ W, int layer,
    float* __restrict__ u, float* __restrict__ v, float4* __restrict__ z_out)
{
    int n = blockIdx.x * 256 + threadIdx.x;
    if (n >= N_NODES) return;
    int k = n / BUCKET;
    int i = n - k * BUCKET;
    float agg = 0.0f;
    const float* pk = partial + (size_t)k * P_SPLIT * BUCKET + i;
#pragma unroll
    for (int p = 0; p < P_SPLIT; ++p) agg += pk[(size_t)p * BUCKET];
    float S = ((layer == 0) ? 0.0f : Sin[n]) + agg;
    if (layer < 2) {
        const float* Wn = W + 12 * (layer + 1);
        float a0 = Wn[0], a1 = Wn[1], a2 = Wn[2], a3 = Wn[3];
        float q0 = Wn[4], q1 = Wn[5], q2 = Wn[6], q3 = Wn[7];
        float A = a0 + a1 + a2 + a3, B = q0 + q1 + q2 + q3;
        float4 zv = z0[n];
        Sout[n] = S;
        u[n] = a0 * zv.x + a1 * zv.y + a2 * zv.z + a3 * zv.w + A * S;
        v[n] = q0 * zv.x + q1 * zv.y + q2 * zv.z + q3 * zv.w + B * S;
    } else {
        float4 zv = z0[n];
        zv.x += S; zv.y += S; zv.z += S; zv.w += S;
        z_out[n] = zv;
    }
}

// ---------------- fallback (round-2) ----------------

__global__ __launch_bounds__(256) void init_kernel(
    const float4* __restrict__ z_in, float4* __restrict__ z_cur,
    float4* __restrict__ x_out, float* __restrict__ agg)
{
    int n = blockIdx.x * blockDim.x + threadIdx.x;
    if (n < N_NODES) {
        float4 vv = z_in[n];
        z_cur[n] = vv; x_out[n] = vv; agg[n] = 0.0f;
    }
}

__global__ __launch_bounds__(256) void edge_kernel(
    const float* __restrict__ z, const float* __restrict__ r,
    const float* __restrict__ r_hat, const int* __restrict__ src,
    const int* __restrict__ dst, const float* __restrict__ Wl,
    const float* __restrict__ bl, float* __restrict__ agg)
{
    int e = blockIdx.x * blockDim.x + threadIdx.x;
    if (e >= N_EDGES) return;
    float w0 = Wl[0], w1 = Wl[1], w2 = Wl[2], w3 = Wl[3];
    float w4 = Wl[4], w5 = Wl[5], w6 = Wl[6], w7 = Wl[7];
    float w8 = Wl[8], w9 = Wl[9], w10 = Wl[10], w11 = Wl[11];
    float bias = bl[0];
    int s = src[e], d = dst[e];
    float4 zs = ((const float4*)z)[s];
    float4 zd = ((const float4*)z)[d];
    float rv = r[e];
    const float* rh = r_hat + 3 * (size_t)e;
    float msg = w0*zs.x + w1*zs.y + w2*zs.z + w3*zs.w
              + w4*zd.x + w5*zd.y + w6*zd.z + w7*zd.w
              + w8*rv + w9*rh[0] + w10*rh[1] + w11*rh[2] + bias;
    unsafeAtomicAdd(&agg[d], msg);
}

__global__ __launch_bounds__(256) void node_update(float4* __restrict__ z_cur,
                                                   float* __restrict__ agg)
{
    int n = blockIdx.x * blockDim.x + threadIdx.x;
    if (n < N_NODES) {
        float a = agg[n]; float4 vv = z_cur[n];
        vv.x += a; vv.y += a; vv.z += a; vv.w += a;
        z_cur[n] = vv; agg[n] = 0.0f;
    }
}

__global__ __launch_bounds__(256) void final_update(const float4* __restrict__ z_cur,
                                                    const float* __restrict__ agg,
                                                    float4* __restrict__ z_out)
{
    int n = blockIdx.x * blockDim.x + threadIdx.x;
    if (n < N_NODES) {
        float a = agg[n]; float4 vv = z_cur[n];
        vv.x += a; vv.y += a; vv.z += a; vv.w += a;
        z_out[n] = vv;
    }
}

// ---------------- launch ----------------

extern "C" void kernel_launch(void* const* d_in, const int* in_sizes, int n_in,
                              void* d_out, int out_size, void* d_ws, size_t ws_size,
                              hipStream_t stream)
{
    const float* z     = (const float*)d_in[0];
    const float* r     = (const float*)d_in[1];
    const float* r_hat = (const float*)d_in[2];
    const float* W     = (const float*)d_in[3];
    const float* b     = (const float*)d_in[4];
    const int*   src   = (const int*)d_in[5];
    const int*   dst   = (const int*)d_in[6];
    float* out = (float*)d_out;

    char* ws = (char*)d_ws;
    size_t off = 0;
    auto alloc = [&](size_t bytes) {
        void* p = ws + off;
        off += (bytes + 15) & ~(size_t)15;
        return p;
    };
    int*            packedA = (int*)alloc((size_t)N_EDGES * 4);
    unsigned*       c01a    = (unsigned*)alloc((size_t)N_EDGES * 4);
    unsigned short* c2a     = (unsigned short*)alloc((size_t)N_EDGES * 2);
    int*            counts  = (int*)alloc((size_t)NSB * K_BUCKETS * 4);
    int*            baseRel = (int*)alloc((size_t)NSB * K_BUCKETS * 4);
    int*            tot     = (int*)alloc((size_t)K_BUCKETS * 4);
    int*            bstart  = (int*)alloc((size_t)(K_BUCKETS + 1) * 4);
    float*          Sa      = (float*)alloc((size_t)N_NODES * 4);
    float*          Sb      = (float*)alloc((size_t)N_NODES * 4);
    float*          ubuf    = (float*)alloc((size_t)N_NODES * 4);
    float*          vbuf    = (float*)alloc((size_t)N_NODES * 4);
    float*          partial = (float*)alloc((size_t)K_BUCKETS * P_SPLIT * BUCKET * 4);
    size_t required = off;

    dim3 nblk((N_NODES + 255) / 256);

    if (ws_size >= required) {
        prep_kernel<<<nblk, 256, 0, stream>>>(
            (const float4*)z, (float4*)(out + 4 * (size_t)N_NODES), W, ubuf, vbuf);
        hist_kernel<<<NSB, 256, 0, stream>>>(dst, counts);
        scan_cols<<<K_BUCKETS, 256, 0, stream>>>(counts, baseRel, tot);
        scan_tot<<<1, 256, 0, stream>>>(tot, bstart);
        scatter_kernel<<<NSB, 256, 0, stream>>>(src, dst, r, r_hat, W, b,
                                                counts, baseRel, bstart,
                                                packedA, c01a, c2a);
        // layer 0
        pagg_kernel<<<K_BUCKETS * P_SPLIT, 256, 0, stream>>>(
            packedA, c01a, c2a, bstart, ubuf, vbuf, 0, partial);
        fin_kernel<<<nblk, 256, 0, stream>>>(
            (const float4*)z, partial, Sa, Sa, W, 0, ubuf, vbuf, (float4*)out);
        // layer 1
        pagg_kernel<<<K_BUCKETS * P_SPLIT, 256, 0, stream>>>(
            packedA, c01a, c2a, bstart, ubuf, vbuf, 1, partial);
        fin_kernel<<<nblk, 256, 0, stream>>>(
            (const float4*)z, partial, Sa, Sb, W, 1, ubuf, vbuf, (float4*)out);
        // layer 2
        pagg_kernel<<<K_BUCKETS * P_SPLIT, 256, 0, stream>>>(
            packedA, c01a, c2a, bstart, ubuf, vbuf, 2, partial);
        fin_kernel<<<nblk, 256, 0, stream>>>(
            (const float4*)z, partial, Sb, Sb, W, 2, ubuf, vbuf, (float4*)out);
    } else {
        // fallback: round-2 path
        float* agg   = (float*)d_ws;
        float* z_cur = agg + N_NODES;
        dim3 eblk((N_EDGES + 255) / 256);
        init_kernel<<<nblk, 256, 0, stream>>>(
            (const float4*)z, (float4*)z_cur,
            (float4*)(out + 4 * (size_t)N_NODES), agg);
        for (int i = 0; i < 3; ++i) {
            edge_kernel<<<eblk, 256, 0, stream>>>(
                z_cur, r, r_hat, src, dst, W + 12 * i, b + i, agg);
            if (i < 2)
                node_update<<<nblk, 256, 0, stream>>>((float4*)z_cur, agg);
            else
                final_update<<<nblk, 256, 0, stream>>>(
                    (const float4*)z_cur, agg, (float4*)out);
        }
    }
}